// Round 3
// baseline (497.749 us; speedup 1.0000x reference)
//
#include <hip/hip_runtime.h>
#include <hip/hip_bf16.h>

// ---- problem constants ----
#define B_ 2
#define L_ 1024
#define HID_ 1536
#define NH_ 24
#define HD_ 64
#define DSSM_ 1536
#define QKV_ 4608

typedef __attribute__((ext_vector_type(8))) short short8;
typedef __attribute__((ext_vector_type(4))) float floatx4;

// =====================================================================
// fp32 -> bf16 cast (n divisible by 1024)
// =====================================================================
__global__ void cast_kernel(const float* __restrict__ in,
                            __hip_bfloat16* __restrict__ out, int n)
{
    int i = (blockIdx.x * 256 + threadIdx.x) * 4;
    if (i < n) {
        float4 f = *reinterpret_cast<const float4*>(in + i);
        out[i]     = __float2bfloat16(f.x);
        out[i + 1] = __float2bfloat16(f.y);
        out[i + 2] = __float2bfloat16(f.z);
        out[i + 3] = __float2bfloat16(f.w);
    }
}

// =====================================================================
// NT GEMM: C[M,N] = A[M,K] @ B[N,K]^T   (A,B row-major bf16, contiguous K)
// block = 256 threads = 4 waves (2x2), block tile 128x128, wave tile 64x64
// OUTMODE: 0 = fp32 out, 1 = fp32 out + fp32 bias, 2 = bf16 out
// =====================================================================
template<int OUTMODE>
__global__ __launch_bounds__(256) void gemm_nt(
    const __hip_bfloat16* __restrict__ A,
    const __hip_bfloat16* __restrict__ Bm,
    void* __restrict__ Cv,
    const float* __restrict__ bias,
    int M, int N, int K)
{
    const int lane  = threadIdx.x & 63;
    const int wave  = threadIdx.x >> 6;
    const int col16 = lane & 15;
    const int quad  = lane >> 4;
    const int row0 = blockIdx.y * 128 + (wave >> 1) * 64;
    const int col0 = blockIdx.x * 128 + (wave & 1) * 64;

    const short* Ap = reinterpret_cast<const short*>(A);
    const short* Bp = reinterpret_cast<const short*>(Bm);

    floatx4 acc[4][4] = {};

    for (int k = 0; k < K; k += 32) {
        short8 af[4], bf[4];
#pragma unroll
        for (int t = 0; t < 4; ++t) {
            af[t] = *reinterpret_cast<const short8*>(
                Ap + (size_t)(row0 + t * 16 + col16) * K + k + quad * 8);
            bf[t] = *reinterpret_cast<const short8*>(
                Bp + (size_t)(col0 + t * 16 + col16) * K + k + quad * 8);
        }
#pragma unroll
        for (int mt = 0; mt < 4; ++mt)
#pragma unroll
            for (int nt = 0; nt < 4; ++nt)
                acc[mt][nt] = __builtin_amdgcn_mfma_f32_16x16x32_bf16(
                    af[mt], bf[nt], acc[mt][nt], 0, 0, 0);
    }

#pragma unroll
    for (int mt = 0; mt < 4; ++mt) {
#pragma unroll
        for (int nt = 0; nt < 4; ++nt) {
#pragma unroll
            for (int r = 0; r < 4; ++r) {
                int row = row0 + mt * 16 + quad * 4 + r;
                int col = col0 + nt * 16 + col16;
                float v = acc[mt][nt][r];
                if (OUTMODE == 1) v += bias[col];
                if (OUTMODE == 2)
                    ((__hip_bfloat16*)Cv)[(size_t)row * N + col] = __float2bfloat16(v);
                else
                    ((float*)Cv)[(size_t)row * N + col] = v;
            }
        }
    }
}

// =====================================================================
// depthwise causal conv (k=2) + SiLU, scatter to q/k/v [B,NH,L,HD] bf16
// raw is bf16 [B,L,QKV]; conv_w fp32 [QKV,2]
// =====================================================================
__global__ void conv_silu_kernel(
    const __hip_bfloat16* __restrict__ raw,
    const float* __restrict__ conv_w,
    __hip_bfloat16* __restrict__ q,
    __hip_bfloat16* __restrict__ k,
    __hip_bfloat16* __restrict__ v)
{
    int idx = blockIdx.x * 256 + threadIdx.x;   // over B*L*QKV
    int c  = idx % QKV_;
    int ml = idx / QKV_;
    int l  = ml % L_;

    float cur  = __bfloat162float(raw[idx]);
    float prev = (l > 0) ? __bfloat162float(raw[idx - QKV_]) : 0.f;
    float u = prev * conv_w[c * 2] + cur * conv_w[c * 2 + 1];
    u = fmaxf(u, -80.f);
    float s = u / (1.f + __expf(-u));           // silu

    int part = c / DSSM_;
    int cc   = c % DSSM_;
    int nh   = cc >> 6;
    int d    = cc & 63;
    int b    = ml / L_;
    __hip_bfloat16* dst = (part == 0) ? q : ((part == 1) ? k : v);
    dst[(((size_t)b * NH_ + nh) * L_ + l) * HD_ + d] = __float2bfloat16(s);
}

// =====================================================================
// dt projection (fp32 x): dt = softplus(x @ w_dt^T + dt_bias); dA = dt*(-exp(a_log))
// one block per (b,l); wave w handles heads w, w+4, ...; outputs [B,NH,L] fp32
// =====================================================================
__global__ __launch_bounds__(256) void dtproj_kernel(
    const float* __restrict__ x,        // [B,L,HID] fp32
    const float* __restrict__ w_dt,     // [NH,HID] fp32
    const float* __restrict__ dt_bias,  // [NH]
    const float* __restrict__ a_log,    // [NH]
    float* __restrict__ dt,
    float* __restrict__ dA)
{
    int m    = blockIdx.x;          // b*L + l
    int b    = m / L_;
    int l    = m % L_;
    int wave = threadIdx.x >> 6;
    int lane = threadIdx.x & 63;
    const float* xr = x + (size_t)m * HID_;

    for (int n = wave; n < NH_; n += 4) {
        float sum = 0.f;
        for (int kk = lane; kk < HID_; kk += 64)
            sum += xr[kk] * w_dt[(size_t)n * HID_ + kk];
#pragma unroll
        for (int off = 32; off; off >>= 1) sum += __shfl_xor(sum, off, 64);
        if (lane == 0) {
            float vdt = sum + dt_bias[n];
            vdt = (vdt > 20.f) ? vdt : log1pf(__expf(vdt));    // softplus
            float Aval = -__expf(a_log[n]);
            size_t o = ((size_t)b * NH_ + n) * L_ + l;
            dt[o] = vdt;
            dA[o] = vdt * Aval;
        }
    }
}

// =====================================================================
// cumsum over L per (b,nh): one wave per block, lane owns 16 consecutive
// =====================================================================
__global__ void cumsum_kernel(const float* __restrict__ dA, float* __restrict__ cs)
{
    int bnh  = blockIdx.x;
    int lane = threadIdx.x;
    const float* src = dA + (size_t)bnh * L_;
    float* dst       = cs + (size_t)bnh * L_;

    float loc[16];
    float run = 0.f;
#pragma unroll
    for (int t = 0; t < 16; ++t) { run += src[lane * 16 + t]; loc[t] = run; }
    float tot = run;
    float sc = tot;
#pragma unroll
    for (int off = 1; off < 64; off <<= 1) {
        float o = __shfl_up(sc, off, 64);
        if (lane >= off) sc += o;
    }
    float offset = sc - tot;   // exclusive prefix of lane totals
#pragma unroll
    for (int t = 0; t < 16; ++t) dst[lane * 16 + t] = loc[t] + offset;
}

// =====================================================================
// quadratic SSD attention, one wave per (b, nh, 16-row i-tile)
// y[b,i,nh,:] = sum_{j<=i} (q_i.k_j) * exp(cs_i-cs_j) * dt_j * v_j  + v_i*D
// QK^T and PV via mfma_f32_16x16x32_bf16; P goes C-layout -> LDS -> A-layout
// =====================================================================
__global__ __launch_bounds__(64) void attn_kernel(
    const __hip_bfloat16* __restrict__ q,   // [B,NH,L,HD] bf16
    const __hip_bfloat16* __restrict__ k,
    const __hip_bfloat16* __restrict__ v,
    const float* __restrict__ dt,           // [B,NH,L]
    const float* __restrict__ cs,           // [B,NH,L]
    const float* __restrict__ Dm,           // [NH,HD] fp32
    float* __restrict__ y)                  // [B,L,DSSM] fp32
{
    const int it   = blockIdx.x;
    const int nh   = blockIdx.y;
    const int b    = blockIdx.z;
    const int lane = threadIdx.x;
    const int col  = lane & 15;
    const int quad = lane >> 4;
    const int bnh  = b * NH_ + nh;
    const int i0   = it * 16;

    const short* qrow = reinterpret_cast<const short*>(q) + ((size_t)bnh * L_ + i0 + col) * HD_;
    short8 aq0 = *reinterpret_cast<const short8*>(qrow + quad * 8);
    short8 aq1 = *reinterpret_cast<const short8*>(qrow + 32 + quad * 8);

    float csr[4];
#pragma unroll
    for (int r = 0; r < 4; ++r) csr[r] = cs[(size_t)bnh * L_ + i0 + quad * 4 + r];

    floatx4 accO[4] = {};
    __shared__ alignas(16) __hip_bfloat16 Pl[16][32];

    const int nch = (i0 + 16 + 31) / 32;
    for (int c = 0; c < nch; ++c) {
        int jc0 = c * 32;
#pragma unroll
        for (int h = 0; h < 2; ++h) {
            int j0 = jc0 + h * 16;
            float p[4] = {0.f, 0.f, 0.f, 0.f};
            if (j0 <= i0 + 15) {
                const short* krow = reinterpret_cast<const short*>(k) + ((size_t)bnh * L_ + j0 + col) * HD_;
                short8 bk0 = *reinterpret_cast<const short8*>(krow + quad * 8);
                short8 bk1 = *reinterpret_cast<const short8*>(krow + 32 + quad * 8);
                floatx4 s = {};
                s = __builtin_amdgcn_mfma_f32_16x16x32_bf16(aq0, bk0, s, 0, 0, 0);
                s = __builtin_amdgcn_mfma_f32_16x16x32_bf16(aq1, bk1, s, 0, 0, 0);
                int j = j0 + col;
                float csj = cs[(size_t)bnh * L_ + j];
                float dtj = dt[(size_t)bnh * L_ + j];
#pragma unroll
                for (int r = 0; r < 4; ++r) {
                    int i = i0 + quad * 4 + r;
                    float e = (j <= i) ? __expf(fminf(csr[r] - csj, 0.f)) : 0.f;
                    p[r] = s[r] * e * dtj;
                }
            }
#pragma unroll
            for (int r = 0; r < 4; ++r)
                Pl[quad * 4 + r][h * 16 + col] = __float2bfloat16(p[r]);
        }
        __syncthreads();
        // read P as A-operand: A[m=col][kk=quad*8+jj]
        short8 pa = *reinterpret_cast<const short8*>(
            reinterpret_cast<const short*>(&Pl[0][0]) + col * 32 + quad * 8);
        const short* vbase = reinterpret_cast<const short*>(v) + ((size_t)bnh * L_ + jc0) * HD_;
#pragma unroll
        for (int nt = 0; nt < 4; ++nt) {
            short8 bv;
#pragma unroll
            for (int jj = 0; jj < 8; ++jj)
                bv[jj] = vbase[(size_t)(quad * 8 + jj) * HD_ + nt * 16 + col];
            accO[nt] = __builtin_amdgcn_mfma_f32_16x16x32_bf16(pa, bv, accO[nt], 0, 0, 0);
        }
        __syncthreads();
    }

    // epilogue: + v_i * D, write y fp32 [B,L,1536]
#pragma unroll
    for (int nt = 0; nt < 4; ++nt) {
#pragma unroll
        for (int r = 0; r < 4; ++r) {
            int i  = i0 + quad * 4 + r;
            int dv = nt * 16 + col;
            float vi = __bfloat162float(v[((size_t)bnh * L_ + i) * HD_ + dv]);
            float val = accO[nt][r] + vi * Dm[nh * HD_ + dv];
            y[((size_t)b * L_ + i) * DSSM_ + nh * HD_ + dv] = val;
        }
    }
}

// =====================================================================
// gate (y * silu(z)) + RMSNorm + rms_w  -> bf16
// one block (256 threads) per (b,l)
// =====================================================================
__global__ __launch_bounds__(256) void gate_rms_kernel(
    const float* __restrict__ y,    // [B,L,DSSM]
    const float* __restrict__ z,    // [B,L,DSSM]
    const float* __restrict__ rms_w,
    __hip_bfloat16* __restrict__ yn)
{
    int m   = blockIdx.x;
    int tid = threadIdx.x;
    const float* yr = y + (size_t)m * DSSM_;
    const float* zr = z + (size_t)m * DSSM_;

    float g[6];
    float ss = 0.f;
#pragma unroll
    for (int t = 0; t < 6; ++t) {
        int c = tid + t * 256;
        float zv = fmaxf(zr[c], -80.f);
        float gv = yr[c] * (zv / (1.f + __expf(-zv)));
        g[t] = gv;
        ss += gv * gv;
    }
#pragma unroll
    for (int off = 32; off; off >>= 1) ss += __shfl_xor(ss, off, 64);
    __shared__ float red[4];
    if ((tid & 63) == 0) red[tid >> 6] = ss;
    __syncthreads();
    ss = red[0] + red[1] + red[2] + red[3];
    float r = rsqrtf(ss / (float)DSSM_ + 1e-6f);
#pragma unroll
    for (int t = 0; t < 6; ++t) {
        int c = tid + t * 256;
        yn[(size_t)m * DSSM_ + c] = __float2bfloat16(g[t] * r * rms_w[c]);
    }
}

// =====================================================================
extern "C" void kernel_launch(void* const* d_in, const int* in_sizes, int n_in,
                              void* d_out, int out_size, void* d_ws, size_t ws_size,
                              hipStream_t stream)
{
    // ALL reference dtypes are float32
    const float* x       = (const float*)d_in[0];
    const float* w_qkv   = (const float*)d_in[1];
    const float* conv_w  = (const float*)d_in[2];
    const float* w_dt    = (const float*)d_in[3];
    const float* dt_bias = (const float*)d_in[4];
    const float* a_log   = (const float*)d_in[5];
    const float* Dm      = (const float*)d_in[6];
    const float* w_z     = (const float*)d_in[7];
    const float* b_z     = (const float*)d_in[8];
    const float* rms_w   = (const float*)d_in[9];
    const float* w_o     = (const float*)d_in[10];
    float* out = (float*)d_out;

    char* ws = (char*)d_ws;
    const int M = B_ * L_;                       // 2048

    // ---- workspace layout (bytes), total ~80.8 MB ----
    __hip_bfloat16* xb    = (__hip_bfloat16*)(ws);                  //  6,291,456
    __hip_bfloat16* wqkvb = (__hip_bfloat16*)(ws + 6291456);        // 14,155,776
    __hip_bfloat16* wzb   = (__hip_bfloat16*)(ws + 20447232);       //  4,718,592
    __hip_bfloat16* wob   = (__hip_bfloat16*)(ws + 25165824);       //  4,718,592
    // slot [29,884,416 .. 48,758,784): qkv bf16 (18,874,368); reused as zbuf fp32 + yn bf16
    __hip_bfloat16* qkvb  = (__hip_bfloat16*)(ws + 29884416);
    float*          zbuf  = (float*)(ws + 29884416);                // 12,582,912
    __hip_bfloat16* yn    = (__hip_bfloat16*)(ws + 42467328);       //  6,291,456
    __hip_bfloat16* qb    = (__hip_bfloat16*)(ws + 48758784);       //  6,291,456
    __hip_bfloat16* kb    = (__hip_bfloat16*)(ws + 55050240);
    __hip_bfloat16* vb    = (__hip_bfloat16*)(ws + 61341696);
    float* dt   = (float*)(ws + 67633152);                          //    196,608
    float* dA   = (float*)(ws + 67829760);
    float* cs   = (float*)(ws + 68026368);
    float* ybuf = (float*)(ws + 68222976);                          // 12,582,912 -> 80,805,888

    // 0) cast fp32 -> bf16 for MFMA operands
    cast_kernel<<<(M * HID_) / 1024, 256, 0, stream>>>(x, xb, M * HID_);
    cast_kernel<<<(QKV_ * HID_) / 1024, 256, 0, stream>>>(w_qkv, wqkvb, QKV_ * HID_);
    cast_kernel<<<(DSSM_ * HID_) / 1024, 256, 0, stream>>>(w_z, wzb, DSSM_ * HID_);
    cast_kernel<<<(HID_ * DSSM_) / 1024, 256, 0, stream>>>(w_o, wob, HID_ * DSSM_);

    // 1) qkv = x @ w_qkv^T          [2048, 4608] bf16
    gemm_nt<2><<<dim3(QKV_ / 128, M / 128), 256, 0, stream>>>(
        xb, wqkvb, (void*)qkvb, nullptr, M, QKV_, HID_);

    // 2) causal conv k=2 + silu -> q,k,v bf16 [B,NH,L,HD]
    conv_silu_kernel<<<(B_ * L_ * QKV_) / 256, 256, 0, stream>>>(
        qkvb, conv_w, qb, kb, vb);

    // 3) dt / dA (fp32 inputs)
    dtproj_kernel<<<M, 256, 0, stream>>>(x, w_dt, dt_bias, a_log, dt, dA);

    // 4) cs = cumsum(dA)
    cumsum_kernel<<<B_ * NH_, 64, 0, stream>>>(dA, cs);

    // 5) attention -> ybuf fp32 [B,L,1536]
    attn_kernel<<<dim3(L_ / 16, NH_, B_), 64, 0, stream>>>(
        qb, kb, vb, dt, cs, Dm, ybuf);

    // 6) z = x @ w_z^T + b_z        [2048, 1536] fp32 (into dead qkv slot)
    gemm_nt<1><<<dim3(DSSM_ / 128, M / 128), 256, 0, stream>>>(
        xb, wzb, (void*)zbuf, b_z, M, DSSM_, HID_);

    // 7) gate + RMSNorm -> yn bf16
    gate_rms_kernel<<<M, 256, 0, stream>>>(ybuf, zbuf, rms_w, yn);

    // 8) out = yn @ w_o^T           [2048, 1536] fp32 output
    gemm_nt<0><<<dim3(HID_ / 128, M / 128), 256, 0, stream>>>(
        yn, wob, (void*)out, nullptr, M, HID_, DSSM_);
}

// Round 4
// 397.729 us; speedup vs baseline: 1.2515x; 1.2515x over previous
//
#include <hip/hip_runtime.h>
#include <hip/hip_bf16.h>

// ---- problem constants ----
#define B_ 2
#define L_ 1024
#define HID_ 1536
#define NH_ 24
#define HD_ 64
#define DSSM_ 1536
#define QKV_ 4608

typedef __attribute__((ext_vector_type(8))) short short8;
typedef __attribute__((ext_vector_type(4))) float floatx4;

// async global -> LDS, 16 bytes per lane (global_load_lds_dwordx4)
__device__ __forceinline__ void gload_lds16(const short* g, short* l)
{
    __builtin_amdgcn_global_load_lds(
        (const __attribute__((address_space(1))) void*)g,
        (__attribute__((address_space(3))) void*)l,
        16, 0, 0);
}

// =====================================================================
// fp32 -> bf16 cast (n divisible by 1024)
// =====================================================================
__global__ void cast_kernel(const float* __restrict__ in,
                            __hip_bfloat16* __restrict__ out, int n)
{
    int i = (blockIdx.x * 256 + threadIdx.x) * 4;
    if (i < n) {
        float4 f = *reinterpret_cast<const float4*>(in + i);
        out[i]     = __float2bfloat16(f.x);
        out[i + 1] = __float2bfloat16(f.y);
        out[i + 2] = __float2bfloat16(f.z);
        out[i + 3] = __float2bfloat16(f.w);
    }
}

// =====================================================================
// NT GEMM, LDS-staged (m97 structure):
// C[M,N] = A[M,K] @ B[N,K]^T, A/B row-major bf16 contiguous-K.
// block = 256 threads = 4 waves (2x2), block tile 128x128, BK=32,
// staging via global_load_lds width=16 (wave-uniform base + lane*16).
// OUTMODE: 0 = fp32 out, 1 = fp32 out + fp32 bias, 2 = bf16 out
// =====================================================================
template<int OUTMODE>
__global__ __launch_bounds__(256) void gemm_nt(
    const __hip_bfloat16* __restrict__ A,
    const __hip_bfloat16* __restrict__ Bm,
    void* __restrict__ Cv,
    const float* __restrict__ bias,
    int M, int N, int K)
{
    const int lane  = threadIdx.x & 63;
    const int wave  = threadIdx.x >> 6;
    const int col16 = lane & 15;
    const int quad  = lane >> 4;
    const int wr    = wave >> 1;          // wave row (0/1)
    const int wc    = wave & 1;           // wave col (0/1)
    const int rowblk = blockIdx.y * 128;
    const int colblk = blockIdx.x * 128;

    const short* Ap = reinterpret_cast<const short*>(A);
    const short* Bp = reinterpret_cast<const short*>(Bm);

    // LDS tiles: [128 rows][32 cols] bf16, row stride 64B, NO padding
    // (global_load_lds lands lane i's 16B at base + i*16 -> row=seg*16+lane/4,
    //  col-chunk=lane&3 -- must match the global fetch mapping exactly)
    __shared__ alignas(16) short As[128 * 32];
    __shared__ alignas(16) short Bs[128 * 32];

    // per-lane staging coords (fixed across K)
    const int srow = lane >> 2;           // 0..15 row within 16-row segment
    const int scol = (lane & 3) * 8;      // short offset of 16B chunk

    floatx4 acc[4][4] = {};

    for (int k0 = 0; k0 < K; k0 += 32) {
#pragma unroll
        for (int s2 = 0; s2 < 2; ++s2) {
            const int seg = wave * 2 + s2;            // 0..7 (16 rows each)
            gload_lds16(Ap + (size_t)(rowblk + seg * 16 + srow) * K + k0 + scol,
                        &As[seg * 512]);
            gload_lds16(Bp + (size_t)(colblk + seg * 16 + srow) * K + k0 + scol,
                        &Bs[seg * 512]);
        }
        __syncthreads();

        short8 af[4], bf[4];
#pragma unroll
        for (int t = 0; t < 4; ++t) {
            af[t] = *reinterpret_cast<const short8*>(
                &As[(wr * 64 + t * 16 + col16) * 32 + quad * 8]);
            bf[t] = *reinterpret_cast<const short8*>(
                &Bs[(wc * 64 + t * 16 + col16) * 32 + quad * 8]);
        }
#pragma unroll
        for (int mt = 0; mt < 4; ++mt)
#pragma unroll
            for (int nt = 0; nt < 4; ++nt)
                acc[mt][nt] = __builtin_amdgcn_mfma_f32_16x16x32_bf16(
                    af[mt], bf[nt], acc[mt][nt], 0, 0, 0);
        __syncthreads();
    }

    const int row0 = rowblk + wr * 64;
    const int col0 = colblk + wc * 64;
#pragma unroll
    for (int mt = 0; mt < 4; ++mt) {
#pragma unroll
        for (int nt = 0; nt < 4; ++nt) {
#pragma unroll
            for (int r = 0; r < 4; ++r) {
                int row = row0 + mt * 16 + quad * 4 + r;
                int col = col0 + nt * 16 + col16;
                float v = acc[mt][nt][r];
                if (OUTMODE == 1) v += bias[col];
                if (OUTMODE == 2)
                    ((__hip_bfloat16*)Cv)[(size_t)row * N + col] = __float2bfloat16(v);
                else
                    ((float*)Cv)[(size_t)row * N + col] = v;
            }
        }
    }
}

// =====================================================================
// depthwise causal conv (k=2) + SiLU, scatter to q/k/v [B,NH,L,HD] bf16
// raw is bf16 [B,L,QKV]; conv_w fp32 [QKV,2]
// =====================================================================
__global__ void conv_silu_kernel(
    const __hip_bfloat16* __restrict__ raw,
    const float* __restrict__ conv_w,
    __hip_bfloat16* __restrict__ q,
    __hip_bfloat16* __restrict__ k,
    __hip_bfloat16* __restrict__ v)
{
    int idx = blockIdx.x * 256 + threadIdx.x;   // over B*L*QKV
    int c  = idx % QKV_;
    int ml = idx / QKV_;
    int l  = ml % L_;

    float cur  = __bfloat162float(raw[idx]);
    float prev = (l > 0) ? __bfloat162float(raw[idx - QKV_]) : 0.f;
    float u = prev * conv_w[c * 2] + cur * conv_w[c * 2 + 1];
    u = fmaxf(u, -80.f);
    float s = u / (1.f + __expf(-u));           // silu

    int part = c / DSSM_;
    int cc   = c % DSSM_;
    int nh   = cc >> 6;
    int d    = cc & 63;
    int b    = ml / L_;
    __hip_bfloat16* dst = (part == 0) ? q : ((part == 1) ? k : v);
    dst[(((size_t)b * NH_ + nh) * L_ + l) * HD_ + d] = __float2bfloat16(s);
}

// =====================================================================
// dt projection (fp32 x): dt = softplus(x @ w_dt^T + dt_bias); dA = dt*(-exp(a_log))
// =====================================================================
__global__ __launch_bounds__(256) void dtproj_kernel(
    const float* __restrict__ x,        // [B,L,HID] fp32
    const float* __restrict__ w_dt,     // [NH,HID] fp32
    const float* __restrict__ dt_bias,  // [NH]
    const float* __restrict__ a_log,    // [NH]
    float* __restrict__ dt,
    float* __restrict__ dA)
{
    int m    = blockIdx.x;          // b*L + l
    int b    = m / L_;
    int l    = m % L_;
    int wave = threadIdx.x >> 6;
    int lane = threadIdx.x & 63;
    const float* xr = x + (size_t)m * HID_;

    for (int n = wave; n < NH_; n += 4) {
        float sum = 0.f;
        for (int kk = lane; kk < HID_; kk += 64)
            sum += xr[kk] * w_dt[(size_t)n * HID_ + kk];
#pragma unroll
        for (int off = 32; off; off >>= 1) sum += __shfl_xor(sum, off, 64);
        if (lane == 0) {
            float vdt = sum + dt_bias[n];
            vdt = (vdt > 20.f) ? vdt : log1pf(__expf(vdt));    // softplus
            float Aval = -__expf(a_log[n]);
            size_t o = ((size_t)b * NH_ + n) * L_ + l;
            dt[o] = vdt;
            dA[o] = vdt * Aval;
        }
    }
}

// =====================================================================
// cumsum over L per (b,nh): one wave per block, lane owns 16 consecutive
// =====================================================================
__global__ void cumsum_kernel(const float* __restrict__ dA, float* __restrict__ cs)
{
    int bnh  = blockIdx.x;
    int lane = threadIdx.x;
    const float* src = dA + (size_t)bnh * L_;
    float* dst       = cs + (size_t)bnh * L_;

    float loc[16];
    float run = 0.f;
#pragma unroll
    for (int t = 0; t < 16; ++t) { run += src[lane * 16 + t]; loc[t] = run; }
    float tot = run;
    float sc = tot;
#pragma unroll
    for (int off = 1; off < 64; off <<= 1) {
        float o = __shfl_up(sc, off, 64);
        if (lane >= off) sc += o;
    }
    float offset = sc - tot;   // exclusive prefix of lane totals
#pragma unroll
    for (int t = 0; t < 16; ++t) dst[lane * 16 + t] = loc[t] + offset;
}

// =====================================================================
// quadratic SSD attention, one wave per (b, nh, 16-row i-tile)
// =====================================================================
__global__ __launch_bounds__(64) void attn_kernel(
    const __hip_bfloat16* __restrict__ q,   // [B,NH,L,HD] bf16
    const __hip_bfloat16* __restrict__ k,
    const __hip_bfloat16* __restrict__ v,
    const float* __restrict__ dt,           // [B,NH,L]
    const float* __restrict__ cs,           // [B,NH,L]
    const float* __restrict__ Dm,           // [NH,HD] fp32
    float* __restrict__ y)                  // [B,L,DSSM] fp32
{
    const int it   = blockIdx.x;
    const int nh   = blockIdx.y;
    const int b    = blockIdx.z;
    const int lane = threadIdx.x;
    const int col  = lane & 15;
    const int quad = lane >> 4;
    const int bnh  = b * NH_ + nh;
    const int i0   = it * 16;

    const short* qrow = reinterpret_cast<const short*>(q) + ((size_t)bnh * L_ + i0 + col) * HD_;
    short8 aq0 = *reinterpret_cast<const short8*>(qrow + quad * 8);
    short8 aq1 = *reinterpret_cast<const short8*>(qrow + 32 + quad * 8);

    float csr[4];
#pragma unroll
    for (int r = 0; r < 4; ++r) csr[r] = cs[(size_t)bnh * L_ + i0 + quad * 4 + r];

    floatx4 accO[4] = {};
    __shared__ alignas(16) __hip_bfloat16 Pl[16][32];

    const int nch = (i0 + 16 + 31) / 32;
    for (int c = 0; c < nch; ++c) {
        int jc0 = c * 32;
#pragma unroll
        for (int h = 0; h < 2; ++h) {
            int j0 = jc0 + h * 16;
            float p[4] = {0.f, 0.f, 0.f, 0.f};
            if (j0 <= i0 + 15) {
                const short* krow = reinterpret_cast<const short*>(k) + ((size_t)bnh * L_ + j0 + col) * HD_;
                short8 bk0 = *reinterpret_cast<const short8*>(krow + quad * 8);
                short8 bk1 = *reinterpret_cast<const short8*>(krow + 32 + quad * 8);
                floatx4 s = {};
                s = __builtin_amdgcn_mfma_f32_16x16x32_bf16(aq0, bk0, s, 0, 0, 0);
                s = __builtin_amdgcn_mfma_f32_16x16x32_bf16(aq1, bk1, s, 0, 0, 0);
                int j = j0 + col;
                float csj = cs[(size_t)bnh * L_ + j];
                float dtj = dt[(size_t)bnh * L_ + j];
#pragma unroll
                for (int r = 0; r < 4; ++r) {
                    int i = i0 + quad * 4 + r;
                    float e = (j <= i) ? __expf(fminf(csr[r] - csj, 0.f)) : 0.f;
                    p[r] = s[r] * e * dtj;
                }
            }
#pragma unroll
            for (int r = 0; r < 4; ++r)
                Pl[quad * 4 + r][h * 16 + col] = __float2bfloat16(p[r]);
        }
        __syncthreads();
        // read P as A-operand: A[m=col][kk=quad*8+jj]
        short8 pa = *reinterpret_cast<const short8*>(
            reinterpret_cast<const short*>(&Pl[0][0]) + col * 32 + quad * 8);
        const short* vbase = reinterpret_cast<const short*>(v) + ((size_t)bnh * L_ + jc0) * HD_;
#pragma unroll
        for (int nt = 0; nt < 4; ++nt) {
            short8 bv;
#pragma unroll
            for (int jj = 0; jj < 8; ++jj)
                bv[jj] = vbase[(size_t)(quad * 8 + jj) * HD_ + nt * 16 + col];
            accO[nt] = __builtin_amdgcn_mfma_f32_16x16x32_bf16(pa, bv, accO[nt], 0, 0, 0);
        }
        __syncthreads();
    }

    // epilogue: + v_i * D, write y fp32 [B,L,1536]
#pragma unroll
    for (int nt = 0; nt < 4; ++nt) {
#pragma unroll
        for (int r = 0; r < 4; ++r) {
            int i  = i0 + quad * 4 + r;
            int dv = nt * 16 + col;
            float vi = __bfloat162float(v[((size_t)bnh * L_ + i) * HD_ + dv]);
            float val = accO[nt][r] + vi * Dm[nh * HD_ + dv];
            y[((size_t)b * L_ + i) * DSSM_ + nh * HD_ + dv] = val;
        }
    }
}

// =====================================================================
// gate (y * silu(z)) + RMSNorm + rms_w  -> bf16
// =====================================================================
__global__ __launch_bounds__(256) void gate_rms_kernel(
    const float* __restrict__ y,    // [B,L,DSSM]
    const float* __restrict__ z,    // [B,L,DSSM]
    const float* __restrict__ rms_w,
    __hip_bfloat16* __restrict__ yn)
{
    int m   = blockIdx.x;
    int tid = threadIdx.x;
    const float* yr = y + (size_t)m * DSSM_;
    const float* zr = z + (size_t)m * DSSM_;

    float g[6];
    float ss = 0.f;
#pragma unroll
    for (int t = 0; t < 6; ++t) {
        int c = tid + t * 256;
        float zv = fmaxf(zr[c], -80.f);
        float gv = yr[c] * (zv / (1.f + __expf(-zv)));
        g[t] = gv;
        ss += gv * gv;
    }
#pragma unroll
    for (int off = 32; off; off >>= 1) ss += __shfl_xor(ss, off, 64);
    __shared__ float red[4];
    if ((tid & 63) == 0) red[tid >> 6] = ss;
    __syncthreads();
    ss = red[0] + red[1] + red[2] + red[3];
    float r = rsqrtf(ss / (float)DSSM_ + 1e-6f);
#pragma unroll
    for (int t = 0; t < 6; ++t) {
        int c = tid + t * 256;
        yn[(size_t)m * DSSM_ + c] = __float2bfloat16(g[t] * r * rms_w[c]);
    }
}

// =====================================================================
extern "C" void kernel_launch(void* const* d_in, const int* in_sizes, int n_in,
                              void* d_out, int out_size, void* d_ws, size_t ws_size,
                              hipStream_t stream)
{
    // ALL reference dtypes are float32
    const float* x       = (const float*)d_in[0];
    const float* w_qkv   = (const float*)d_in[1];
    const float* conv_w  = (const float*)d_in[2];
    const float* w_dt    = (const float*)d_in[3];
    const float* dt_bias = (const float*)d_in[4];
    const float* a_log   = (const float*)d_in[5];
    const float* Dm      = (const float*)d_in[6];
    const float* w_z     = (const float*)d_in[7];
    const float* b_z     = (const float*)d_in[8];
    const float* rms_w   = (const float*)d_in[9];
    const float* w_o     = (const float*)d_in[10];
    float* out = (float*)d_out;

    char* ws = (char*)d_ws;
    const int M = B_ * L_;                       // 2048

    // ---- workspace layout (bytes), total ~80.8 MB ----
    __hip_bfloat16* xb    = (__hip_bfloat16*)(ws);                  //  6,291,456
    __hip_bfloat16* wqkvb = (__hip_bfloat16*)(ws + 6291456);        // 14,155,776
    __hip_bfloat16* wzb   = (__hip_bfloat16*)(ws + 20447232);       //  4,718,592
    __hip_bfloat16* wob   = (__hip_bfloat16*)(ws + 25165824);       //  4,718,592
    // slot [29,884,416 .. 48,758,784): qkv bf16 (18,874,368); reused as zbuf fp32 + yn bf16
    __hip_bfloat16* qkvb  = (__hip_bfloat16*)(ws + 29884416);
    float*          zbuf  = (float*)(ws + 29884416);                // 12,582,912
    __hip_bfloat16* yn    = (__hip_bfloat16*)(ws + 42467328);       //  6,291,456
    __hip_bfloat16* qb    = (__hip_bfloat16*)(ws + 48758784);       //  6,291,456
    __hip_bfloat16* kb    = (__hip_bfloat16*)(ws + 55050240);
    __hip_bfloat16* vb    = (__hip_bfloat16*)(ws + 61341696);
    float* dt   = (float*)(ws + 67633152);                          //    196,608
    float* dA   = (float*)(ws + 67829760);
    float* cs   = (float*)(ws + 68026368);
    float* ybuf = (float*)(ws + 68222976);                          // 12,582,912 -> 80,805,888

    // 0) cast fp32 -> bf16 for MFMA operands
    cast_kernel<<<(M * HID_) / 1024, 256, 0, stream>>>(x, xb, M * HID_);
    cast_kernel<<<(QKV_ * HID_) / 1024, 256, 0, stream>>>(w_qkv, wqkvb, QKV_ * HID_);
    cast_kernel<<<(DSSM_ * HID_) / 1024, 256, 0, stream>>>(w_z, wzb, DSSM_ * HID_);
    cast_kernel<<<(HID_ * DSSM_) / 1024, 256, 0, stream>>>(w_o, wob, HID_ * DSSM_);

    // 1) qkv = x @ w_qkv^T          [2048, 4608] bf16
    gemm_nt<2><<<dim3(QKV_ / 128, M / 128), 256, 0, stream>>>(
        xb, wqkvb, (void*)qkvb, nullptr, M, QKV_, HID_);

    // 2) causal conv k=2 + silu -> q,k,v bf16 [B,NH,L,HD]
    conv_silu_kernel<<<(B_ * L_ * QKV_) / 256, 256, 0, stream>>>(
        qkvb, conv_w, qb, kb, vb);

    // 3) dt / dA (fp32 inputs)
    dtproj_kernel<<<M, 256, 0, stream>>>(x, w_dt, dt_bias, a_log, dt, dA);

    // 4) cs = cumsum(dA)
    cumsum_kernel<<<B_ * NH_, 64, 0, stream>>>(dA, cs);

    // 5) attention -> ybuf fp32 [B,L,1536]
    attn_kernel<<<dim3(L_ / 16, NH_, B_), 64, 0, stream>>>(
        qb, kb, vb, dt, cs, Dm, ybuf);

    // 6) z = x @ w_z^T + b_z        [2048, 1536] fp32 (into dead qkv slot)
    gemm_nt<1><<<dim3(DSSM_ / 128, M / 128), 256, 0, stream>>>(
        xb, wzb, (void*)zbuf, b_z, M, DSSM_, HID_);

    // 7) gate + RMSNorm -> yn bf16
    gate_rms_kernel<<<M, 256, 0, stream>>>(ybuf, zbuf, rms_w, yn);

    // 8) out = yn @ w_o^T           [2048, 1536] fp32 output
    gemm_nt<0><<<dim3(HID_ / 128, M / 128), 256, 0, stream>>>(
        yn, wob, (void*)out, nullptr, M, HID_, DSSM_);
}

// Round 5
// 391.966 us; speedup vs baseline: 1.2699x; 1.0147x over previous
//
#include <hip/hip_runtime.h>
#include <hip/hip_bf16.h>

// ---- problem constants ----
#define B_ 2
#define L_ 1024
#define HID_ 1536
#define NH_ 24
#define HD_ 64
#define DSSM_ 1536
#define QKV_ 4608

typedef __attribute__((ext_vector_type(8))) short short8;
typedef __attribute__((ext_vector_type(4))) float floatx4;

// async global -> LDS, 16 bytes per lane (global_load_lds_dwordx4)
__device__ __forceinline__ void gload_lds16(const short* g, short* l)
{
    __builtin_amdgcn_global_load_lds(
        (const __attribute__((address_space(1))) void*)g,
        (__attribute__((address_space(3))) void*)l,
        16, 0, 0);
}

__device__ __forceinline__ float bfs2f(short s)
{
    unsigned u = ((unsigned)(unsigned short)s) << 16;
    float f; __builtin_memcpy(&f, &u, 4); return f;
}
__device__ __forceinline__ short f2bfs(float f)
{
    __hip_bfloat16 h = __float2bfloat16(f);
    short s; __builtin_memcpy(&s, &h, 2); return s;
}

// =====================================================================
// fp32 -> bf16 cast (n divisible by 1024)
// =====================================================================
__global__ void cast_kernel(const float* __restrict__ in,
                            __hip_bfloat16* __restrict__ out, int n)
{
    int i = (blockIdx.x * 256 + threadIdx.x) * 4;
    if (i < n) {
        float4 f = *reinterpret_cast<const float4*>(in + i);
        out[i]     = __float2bfloat16(f.x);
        out[i + 1] = __float2bfloat16(f.y);
        out[i + 2] = __float2bfloat16(f.z);
        out[i + 3] = __float2bfloat16(f.w);
    }
}

// =====================================================================
// NT GEMM, LDS-staged (m97 structure) — unchanged from round 4
// =====================================================================
template<int OUTMODE>
__global__ __launch_bounds__(256) void gemm_nt(
    const __hip_bfloat16* __restrict__ A,
    const __hip_bfloat16* __restrict__ Bm,
    void* __restrict__ Cv,
    const float* __restrict__ bias,
    int M, int N, int K)
{
    const int lane  = threadIdx.x & 63;
    const int wave  = threadIdx.x >> 6;
    const int col16 = lane & 15;
    const int quad  = lane >> 4;
    const int wr    = wave >> 1;
    const int wc    = wave & 1;
    const int rowblk = blockIdx.y * 128;
    const int colblk = blockIdx.x * 128;

    const short* Ap = reinterpret_cast<const short*>(A);
    const short* Bp = reinterpret_cast<const short*>(Bm);

    __shared__ alignas(16) short As[128 * 32];
    __shared__ alignas(16) short Bs[128 * 32];

    const int srow = lane >> 2;
    const int scol = (lane & 3) * 8;

    floatx4 acc[4][4] = {};

    for (int k0 = 0; k0 < K; k0 += 32) {
#pragma unroll
        for (int s2 = 0; s2 < 2; ++s2) {
            const int seg = wave * 2 + s2;
            gload_lds16(Ap + (size_t)(rowblk + seg * 16 + srow) * K + k0 + scol,
                        &As[seg * 512]);
            gload_lds16(Bp + (size_t)(colblk + seg * 16 + srow) * K + k0 + scol,
                        &Bs[seg * 512]);
        }
        __syncthreads();

        short8 af[4], bf[4];
#pragma unroll
        for (int t = 0; t < 4; ++t) {
            af[t] = *reinterpret_cast<const short8*>(
                &As[(wr * 64 + t * 16 + col16) * 32 + quad * 8]);
            bf[t] = *reinterpret_cast<const short8*>(
                &Bs[(wc * 64 + t * 16 + col16) * 32 + quad * 8]);
        }
#pragma unroll
        for (int mt = 0; mt < 4; ++mt)
#pragma unroll
            for (int nt = 0; nt < 4; ++nt)
                acc[mt][nt] = __builtin_amdgcn_mfma_f32_16x16x32_bf16(
                    af[mt], bf[nt], acc[mt][nt], 0, 0, 0);
        __syncthreads();
    }

    const int row0 = rowblk + wr * 64;
    const int col0 = colblk + wc * 64;
#pragma unroll
    for (int mt = 0; mt < 4; ++mt) {
#pragma unroll
        for (int nt = 0; nt < 4; ++nt) {
#pragma unroll
            for (int r = 0; r < 4; ++r) {
                int row = row0 + mt * 16 + quad * 4 + r;
                int col = col0 + nt * 16 + col16;
                float v = acc[mt][nt][r];
                if (OUTMODE == 1) v += bias[col];
                if (OUTMODE == 2)
                    ((__hip_bfloat16*)Cv)[(size_t)row * N + col] = __float2bfloat16(v);
                else
                    ((float*)Cv)[(size_t)row * N + col] = v;
            }
        }
    }
}

// =====================================================================
// depthwise causal conv (k=2) + SiLU -> q/k/v [B,NH,L,HD] bf16
// =====================================================================
__global__ void conv_silu_kernel(
    const __hip_bfloat16* __restrict__ raw,
    const float* __restrict__ conv_w,
    __hip_bfloat16* __restrict__ q,
    __hip_bfloat16* __restrict__ k,
    __hip_bfloat16* __restrict__ v)
{
    int idx = blockIdx.x * 256 + threadIdx.x;   // over B*L*QKV
    int c  = idx % QKV_;
    int ml = idx / QKV_;
    int l  = ml % L_;

    float cur  = __bfloat162float(raw[idx]);
    float prev = (l > 0) ? __bfloat162float(raw[idx - QKV_]) : 0.f;
    float u = prev * conv_w[c * 2] + cur * conv_w[c * 2 + 1];
    u = fmaxf(u, -80.f);
    float s = u / (1.f + __expf(-u));           // silu

    int part = c / DSSM_;
    int cc   = c % DSSM_;
    int nh   = cc >> 6;
    int d    = cc & 63;
    int b    = ml / L_;
    __hip_bfloat16* dst = (part == 0) ? q : ((part == 1) ? k : v);
    dst[(((size_t)b * NH_ + nh) * L_ + l) * HD_ + d] = __float2bfloat16(s);
}

// =====================================================================
// dt projection (fp32): dt = softplus(x @ w_dt^T + dt_bias); dA = dt*(-exp(a_log))
// =====================================================================
__global__ __launch_bounds__(256) void dtproj_kernel(
    const float* __restrict__ x,
    const float* __restrict__ w_dt,
    const float* __restrict__ dt_bias,
    const float* __restrict__ a_log,
    float* __restrict__ dt,
    float* __restrict__ dA)
{
    int m    = blockIdx.x;
    int b    = m / L_;
    int l    = m % L_;
    int wave = threadIdx.x >> 6;
    int lane = threadIdx.x & 63;
    const float* xr = x + (size_t)m * HID_;

    for (int n = wave; n < NH_; n += 4) {
        float sum = 0.f;
        for (int kk = lane; kk < HID_; kk += 64)
            sum += xr[kk] * w_dt[(size_t)n * HID_ + kk];
#pragma unroll
        for (int off = 32; off; off >>= 1) sum += __shfl_xor(sum, off, 64);
        if (lane == 0) {
            float vdt = sum + dt_bias[n];
            vdt = (vdt > 20.f) ? vdt : log1pf(__expf(vdt));
            float Aval = -__expf(a_log[n]);
            size_t o = ((size_t)b * NH_ + n) * L_ + l;
            dt[o] = vdt;
            dA[o] = vdt * Aval;
        }
    }
}

// =====================================================================
// cumsum over L per (b,nh)
// =====================================================================
__global__ void cumsum_kernel(const float* __restrict__ dA, float* __restrict__ cs)
{
    int bnh  = blockIdx.x;
    int lane = threadIdx.x;
    const float* src = dA + (size_t)bnh * L_;
    float* dst       = cs + (size_t)bnh * L_;

    float loc[16];
    float run = 0.f;
#pragma unroll
    for (int t = 0; t < 16; ++t) { run += src[lane * 16 + t]; loc[t] = run; }
    float tot = run;
    float sc = tot;
#pragma unroll
    for (int off = 1; off < 64; off <<= 1) {
        float o = __shfl_up(sc, off, 64);
        if (lane >= off) sc += o;
    }
    float offset = sc - tot;
#pragma unroll
    for (int t = 0; t < 16; ++t) dst[lane * 16 + t] = loc[t] + offset;
}

// =====================================================================
// V -> Vt transpose with dt folding: vt[b,nh,d,l] = v[b,nh,l,d] * dt[b,nh,l]
// grid (L/64, NH, B), 256 threads, 64x64 tile via LDS
// =====================================================================
__global__ __launch_bounds__(256) void vdt_transpose_kernel(
    const __hip_bfloat16* __restrict__ v,   // [B,NH,L,HD]
    const float* __restrict__ dt,           // [B,NH,L]
    __hip_bfloat16* __restrict__ vt)        // [B,NH,HD,L] (dt-scaled)
{
    const int lt0 = blockIdx.x * 64;
    const int bnh = blockIdx.z * NH_ + blockIdx.y;
    const int tid = threadIdx.x;

    __shared__ short T[64][72];

    {
        int row = tid >> 2;
        int cc  = (tid & 3) * 16;
        const short* sp = reinterpret_cast<const short*>(v)
                        + ((size_t)bnh * L_ + lt0 + row) * HD_ + cc;
        float dtr = dt[(size_t)bnh * L_ + lt0 + row];
        short8 a = *reinterpret_cast<const short8*>(sp);
        short8 b = *reinterpret_cast<const short8*>(sp + 8);
#pragma unroll
        for (int j = 0; j < 8; ++j) {
            T[row][cc + j]     = f2bfs(bfs2f(a[j]) * dtr);
            T[row][cc + 8 + j] = f2bfs(bfs2f(b[j]) * dtr);
        }
    }
    __syncthreads();
    {
        int d  = tid >> 2;
        int lc = (tid & 3) * 16;
        short8 o0, o1;
#pragma unroll
        for (int j = 0; j < 8; ++j) {
            o0[j] = T[lc + j][d];
            o1[j] = T[lc + 8 + j][d];
        }
        short* dst = reinterpret_cast<short*>(vt)
                   + ((size_t)bnh * HD_ + d) * L_ + lt0 + lc;
        *reinterpret_cast<short8*>(dst)     = o0;
        *reinterpret_cast<short8*>(dst + 8) = o1;
    }
}

// =====================================================================
// quadratic SSD attention — 4-wave blocks over 64-row i-tiles.
// K tile staged once/block via global_load_lds ([2][64][32] layout);
// Vt (dt-scaled, transposed) read directly from global as short8;
// P round-trips through per-wave LDS (stride 72).
// =====================================================================
__global__ __launch_bounds__(256) void attn_kernel(
    const __hip_bfloat16* __restrict__ q,   // [B,NH,L,HD]
    const __hip_bfloat16* __restrict__ k,   // [B,NH,L,HD]
    const __hip_bfloat16* __restrict__ vt,  // [B,NH,HD,L], dt-scaled
    const __hip_bfloat16* __restrict__ v,   // [B,NH,L,HD] (for D skip)
    const float* __restrict__ cs,           // [B,NH,L]
    const float* __restrict__ Dm,           // [NH,HD] fp32
    float* __restrict__ y)                  // [B,L,DSSM] fp32
{
    const int ib   = blockIdx.x;
    const int nh   = blockIdx.y;
    const int b    = blockIdx.z;
    const int tid  = threadIdx.x;
    const int lane = tid & 63;
    const int wave = tid >> 6;
    const int col  = lane & 15;
    const int quad = lane >> 4;
    const int bnh  = b * NH_ + nh;
    const int i0b  = ib * 64;
    const int iw0  = i0b + wave * 16;     // this wave's 16 i-rows

    const short* qp  = reinterpret_cast<const short*>(q);
    const short* kp  = reinterpret_cast<const short*>(k);
    const short* vtp = reinterpret_cast<const short*>(vt);

    __shared__ alignas(16) short Ks[4096];        // [2][64 rows][32] (HD halves)
    __shared__ alignas(16) short Ps[4 * 16 * 72]; // per-wave 16x72 P tile

    // Q fragments (A-layout): rows iw0+col, k-chunks quad*8 (+32)
    const short* qrow = qp + ((size_t)bnh * L_ + iw0 + col) * HD_;
    short8 aq0 = *reinterpret_cast<const short8*>(qrow + quad * 8);
    short8 aq1 = *reinterpret_cast<const short8*>(qrow + 32 + quad * 8);

    float csr[4];
#pragma unroll
    for (int r = 0; r < 4; ++r)
        csr[r] = cs[(size_t)bnh * L_ + iw0 + quad * 4 + r];

    floatx4 accO[4] = {};

    for (int j0 = 0; j0 <= i0b; j0 += 64) {
        // ---- stage K tile: rows j0..j0+63, [2][64][32] ----
        {
            const short* gk = kp + ((size_t)bnh * L_ + j0 + wave * 16 + (lane >> 2)) * HD_
                            + (lane & 3) * 8;
            gload_lds16(gk,      &Ks[wave * 512 + lane * 8]);
            gload_lds16(gk + 32, &Ks[2048 + wave * 512 + lane * 8]);
        }
        __syncthreads();

        // ---- QK^T + decay -> Ps (per-wave) ----
#pragma unroll
        for (int s = 0; s < 4; ++s) {
            int jsub = j0 + s * 16;
            if (jsub <= iw0 + 15) {
                short8 bk0 = *reinterpret_cast<const short8*>(
                    &Ks[(s * 16 + col) * 32 + quad * 8]);
                short8 bk1 = *reinterpret_cast<const short8*>(
                    &Ks[2048 + (s * 16 + col) * 32 + quad * 8]);
                floatx4 sc = {};
                sc = __builtin_amdgcn_mfma_f32_16x16x32_bf16(aq0, bk0, sc, 0, 0, 0);
                sc = __builtin_amdgcn_mfma_f32_16x16x32_bf16(aq1, bk1, sc, 0, 0, 0);
                int j = jsub + col;
                float csj = cs[(size_t)bnh * L_ + j];
#pragma unroll
                for (int r = 0; r < 4; ++r) {
                    int i = iw0 + quad * 4 + r;
                    float e = (j <= i) ? __expf(csr[r] - csj) : 0.f;
                    Ps[wave * 1152 + (quad * 4 + r) * 72 + s * 16 + col] =
                        f2bfs(sc[r] * e);
                }
            } else if (j0 + (s >> 1) * 32 <= iw0 + 15) {
#pragma unroll
                for (int r = 0; r < 4; ++r)
                    Ps[wave * 1152 + (quad * 4 + r) * 72 + s * 16 + col] = 0;
            }
        }

        // ---- PV: accO += P @ V (Vt is dt-scaled) ----
        for (int c = 0; c < 2; ++c) {
            if (j0 + c * 32 > iw0 + 15) continue;
            short8 pa = *reinterpret_cast<const short8*>(
                &Ps[wave * 1152 + col * 72 + c * 32 + quad * 8]);
#pragma unroll
            for (int nt = 0; nt < 4; ++nt) {
                short8 bv = *reinterpret_cast<const short8*>(
                    vtp + ((size_t)bnh * HD_ + nt * 16 + col) * L_
                        + j0 + c * 32 + quad * 8);
                accO[nt] = __builtin_amdgcn_mfma_f32_16x16x32_bf16(pa, bv, accO[nt], 0, 0, 0);
            }
        }
        __syncthreads();
    }

    // ---- epilogue: + v_i * D, write y fp32 [B,L,1536] ----
#pragma unroll
    for (int nt = 0; nt < 4; ++nt) {
#pragma unroll
        for (int r = 0; r < 4; ++r) {
            int i  = iw0 + quad * 4 + r;
            int dv = nt * 16 + col;
            float vi = __bfloat162float(v[((size_t)bnh * L_ + i) * HD_ + dv]);
            float val = accO[nt][r] + vi * Dm[nh * HD_ + dv];
            y[((size_t)b * L_ + i) * DSSM_ + nh * HD_ + dv] = val;
        }
    }
}

// =====================================================================
// gate (y * silu(z)) + RMSNorm + rms_w  -> bf16
// =====================================================================
__global__ __launch_bounds__(256) void gate_rms_kernel(
    const float* __restrict__ y,
    const float* __restrict__ z,
    const float* __restrict__ rms_w,
    __hip_bfloat16* __restrict__ yn)
{
    int m   = blockIdx.x;
    int tid = threadIdx.x;
    const float* yr = y + (size_t)m * DSSM_;
    const float* zr = z + (size_t)m * DSSM_;

    float g[6];
    float ss = 0.f;
#pragma unroll
    for (int t = 0; t < 6; ++t) {
        int c = tid + t * 256;
        float zv = fmaxf(zr[c], -80.f);
        float gv = yr[c] * (zv / (1.f + __expf(-zv)));
        g[t] = gv;
        ss += gv * gv;
    }
#pragma unroll
    for (int off = 32; off; off >>= 1) ss += __shfl_xor(ss, off, 64);
    __shared__ float red[4];
    if ((tid & 63) == 0) red[tid >> 6] = ss;
    __syncthreads();
    ss = red[0] + red[1] + red[2] + red[3];
    float r = rsqrtf(ss / (float)DSSM_ + 1e-6f);
#pragma unroll
    for (int t = 0; t < 6; ++t) {
        int c = tid + t * 256;
        yn[(size_t)m * DSSM_ + c] = __float2bfloat16(g[t] * r * rms_w[c]);
    }
}

// =====================================================================
extern "C" void kernel_launch(void* const* d_in, const int* in_sizes, int n_in,
                              void* d_out, int out_size, void* d_ws, size_t ws_size,
                              hipStream_t stream)
{
    const float* x       = (const float*)d_in[0];
    const float* w_qkv   = (const float*)d_in[1];
    const float* conv_w  = (const float*)d_in[2];
    const float* w_dt    = (const float*)d_in[3];
    const float* dt_bias = (const float*)d_in[4];
    const float* a_log   = (const float*)d_in[5];
    const float* Dm      = (const float*)d_in[6];
    const float* w_z     = (const float*)d_in[7];
    const float* b_z     = (const float*)d_in[8];
    const float* rms_w   = (const float*)d_in[9];
    const float* w_o     = (const float*)d_in[10];
    float* out = (float*)d_out;

    char* ws = (char*)d_ws;
    const int M = B_ * L_;                       // 2048

    // ---- workspace layout (bytes), total ~80.8 MB ----
    __hip_bfloat16* xb    = (__hip_bfloat16*)(ws);                  //  6,291,456
    __hip_bfloat16* wqkvb = (__hip_bfloat16*)(ws + 6291456);        // 14,155,776
    __hip_bfloat16* wzb   = (__hip_bfloat16*)(ws + 20447232);       //  4,718,592
    __hip_bfloat16* wob   = (__hip_bfloat16*)(ws + 25165824);       //  4,718,592
    // slot [29,884,416 .. 48,758,784): qkv bf16; later: vtb (pre-attn) then zbuf+yn (post-attn)
    __hip_bfloat16* qkvb  = (__hip_bfloat16*)(ws + 29884416);       // 18,874,368
    __hip_bfloat16* vtb   = (__hip_bfloat16*)(ws + 29884416);       //  6,291,456 (lifetime: transpose->attn)
    float*          zbuf  = (float*)(ws + 29884416);                // 12,582,912 (lifetime: step6->7)
    __hip_bfloat16* yn    = (__hip_bfloat16*)(ws + 42467328);       //  6,291,456
    __hip_bfloat16* qb    = (__hip_bfloat16*)(ws + 48758784);       //  6,291,456
    __hip_bfloat16* kb    = (__hip_bfloat16*)(ws + 55050240);
    __hip_bfloat16* vb    = (__hip_bfloat16*)(ws + 61341696);
    float* dt   = (float*)(ws + 67633152);
    float* dA   = (float*)(ws + 67829760);
    float* cs   = (float*)(ws + 68026368);
    float* ybuf = (float*)(ws + 68222976);                          // -> 80,805,888

    // 0) casts
    cast_kernel<<<(M * HID_) / 1024, 256, 0, stream>>>(x, xb, M * HID_);
    cast_kernel<<<(QKV_ * HID_) / 1024, 256, 0, stream>>>(w_qkv, wqkvb, QKV_ * HID_);
    cast_kernel<<<(DSSM_ * HID_) / 1024, 256, 0, stream>>>(w_z, wzb, DSSM_ * HID_);
    cast_kernel<<<(HID_ * DSSM_) / 1024, 256, 0, stream>>>(w_o, wob, HID_ * DSSM_);

    // 1) qkv = x @ w_qkv^T
    gemm_nt<2><<<dim3(QKV_ / 128, M / 128), 256, 0, stream>>>(
        xb, wqkvb, (void*)qkvb, nullptr, M, QKV_, HID_);

    // 2) conv + silu -> q,k,v
    conv_silu_kernel<<<(B_ * L_ * QKV_) / 256, 256, 0, stream>>>(
        qkvb, conv_w, qb, kb, vb);

    // 3) dt / dA
    dtproj_kernel<<<M, 256, 0, stream>>>(x, w_dt, dt_bias, a_log, dt, dA);

    // 4) cs = cumsum(dA)
    cumsum_kernel<<<B_ * NH_, 64, 0, stream>>>(dA, cs);

    // 5a) vt = transpose(v) * dt   (qkvb dead; vtb aliases its slot)
    vdt_transpose_kernel<<<dim3(L_ / 64, NH_, B_), 256, 0, stream>>>(vb, dt, vtb);

    // 5b) attention -> ybuf
    attn_kernel<<<dim3(L_ / 64, NH_, B_), 256, 0, stream>>>(
        qb, kb, vtb, vb, cs, Dm, ybuf);

    // 6) z = x @ w_z^T + b_z   (vtb dead; zbuf aliases)
    gemm_nt<1><<<dim3(DSSM_ / 128, M / 128), 256, 0, stream>>>(
        xb, wzb, (void*)zbuf, b_z, M, DSSM_, HID_);

    // 7) gate + RMSNorm -> yn
    gate_rms_kernel<<<M, 256, 0, stream>>>(ybuf, zbuf, rms_w, yn);

    // 8) out = yn @ w_o^T
    gemm_nt<0><<<dim3(HID_ / 128, M / 128), 256, 0, stream>>>(
        yn, wob, (void*)out, nullptr, M, HID_, DSSM_);
}